// Round 1
// baseline (239.855 us; speedup 1.0000x reference)
//
#include <hip/hip_runtime.h>
#include <hip/hip_bf16.h>

#define SEQ 8192
#define EMB 512
#define ATT 64

typedef __bf16 bf16x8 __attribute__((ext_vector_type(8)));
typedef float  f32x4  __attribute__((ext_vector_type(4)));

static __device__ __forceinline__ __bf16 tobf(float f) { return (__bf16)f; }

// ---------------------------------------------------------------------------
// Kernel 1: QKV projection.
// grid = SEQ/BR blocks, block = 192 threads; thread t owns (matrix m = t/64,
// col c = t%64). Stages BR rows of X in LDS; inner loop broadcasts x, each
// thread streams its W row (float4). Writes:
//   Qs [SEQ][ATT] bf16, pre-scaled by 0.125 (= 1/sqrt(64), exact)
//   Kb [SEQ][ATT] bf16
//   VT [ATT][SEQ] bf16  (transposed so PV A-operand loads are contiguous)
// ---------------------------------------------------------------------------
#define BR 16
__global__ __launch_bounds__(192) void qkv_kernel(
    const float* __restrict__ X,
    const float* __restrict__ Wq, const float* __restrict__ bq,
    const float* __restrict__ Wk, const float* __restrict__ bk,
    const float* __restrict__ Wv, const float* __restrict__ bv,
    __bf16* __restrict__ Qs, __bf16* __restrict__ Kb, __bf16* __restrict__ VT)
{
    __shared__ float xs[BR][EMB];
    const int t    = threadIdx.x;
    const int row0 = blockIdx.x * BR;

    // cooperative load of BR rows of X (float4-vectorized, coalesced)
    {
        const float4* Xv  = (const float4*)(X + (size_t)row0 * EMB);
        float4*       xsv = (float4*)&xs[0][0];
        for (int i = t; i < BR * EMB / 4; i += 192) xsv[i] = Xv[i];
    }
    __syncthreads();

    const int m = t / 64;
    const int c = t % 64;
    const float* W    = (m == 0 ? Wq : (m == 1 ? Wk : Wv)) + (size_t)c * EMB;
    const float  bias = (m == 0 ? bq : (m == 1 ? bk : bv))[c];

    float acc[BR];
#pragma unroll
    for (int r = 0; r < BR; ++r) acc[r] = bias;

    for (int k = 0; k < EMB; k += 4) {
        const float4 w4 = *(const float4*)(W + k);
#pragma unroll
        for (int r = 0; r < BR; ++r) {
            acc[r] += xs[r][k]     * w4.x;
            acc[r] += xs[r][k + 1] * w4.y;
            acc[r] += xs[r][k + 2] * w4.z;
            acc[r] += xs[r][k + 3] * w4.w;
        }
    }

    if (m == 0) {
#pragma unroll
        for (int r = 0; r < BR; ++r)
            Qs[(size_t)(row0 + r) * ATT + c] = tobf(acc[r] * 0.125f);
    } else if (m == 1) {
#pragma unroll
        for (int r = 0; r < BR; ++r)
            Kb[(size_t)(row0 + r) * ATT + c] = tobf(acc[r]);
    } else {
#pragma unroll
        for (int r = 0; r < BR; ++r)
            VT[(size_t)c * SEQ + row0 + r] = tobf(acc[r]);
    }
}

// ---------------------------------------------------------------------------
// Kernel 2: flash attention, one wave per 16 q-rows.
// Swapped QK^T: scores^T = K_tile(16xK) x Q^T(Kx16) so q = lane&15 and the
// softmax row-reduce is 2 shfl_xor. P^T routed through per-wave LDS [q][key]
// to convert C-layout -> B-fragment layout for PV.  O^T = V^T x P^T.
// ---------------------------------------------------------------------------
__global__ __launch_bounds__(64) void flash_kernel(
    const __bf16* __restrict__ Qs,
    const __bf16* __restrict__ Kb,
    const __bf16* __restrict__ VT,
    float* __restrict__ Out)
{
    __shared__ __bf16 p2[16][32];   // [q][key within chunk], one wave per block

    const int lane  = threadIdx.x;  // 0..63
    const int g     = lane >> 4;    // k-group 0..3
    const int ql    = lane & 15;    // q col within tile
    const int qbase = blockIdx.x * 16;

    // Q fragments (B operand of both QK MFMAs): B[k][q] = Qs[qbase+ql][k]
    bf16x8 qfrag0 = *(const bf16x8*)(Qs + (size_t)(qbase + ql) * ATT + g * 8);
    bf16x8 qfrag1 = *(const bf16x8*)(Qs + (size_t)(qbase + ql) * ATT + 32 + g * 8);

    float m = -1e30f, l = 0.f;
    f32x4 o[4] = {};                // O^T d-tiles (d = dt*16 + g*4 + r, q = ql)

    for (int kb = 0; kb < SEQ; kb += 32) {
        // ---- QK^T (swapped): st[t2] = scores^T tile [16 keys x 16 q] ----
        f32x4 st[2];
        st[0] = f32x4{0.f, 0.f, 0.f, 0.f};
        st[1] = f32x4{0.f, 0.f, 0.f, 0.f};
#pragma unroll
        for (int t2 = 0; t2 < 2; ++t2) {
            const __bf16* kp = Kb + (size_t)(kb + t2 * 16 + ql) * ATT + g * 8;
            bf16x8 ka0 = *(const bf16x8*)(kp);
            bf16x8 ka1 = *(const bf16x8*)(kp + 32);
            st[t2] = __builtin_amdgcn_mfma_f32_16x16x32_bf16(ka0, qfrag0, st[t2], 0, 0, 0);
            st[t2] = __builtin_amdgcn_mfma_f32_16x16x32_bf16(ka1, qfrag1, st[t2], 0, 0, 0);
        }
        // st[t2][r] = S^T[key = kb + t2*16 + g*4 + r][q = ql]  (already scaled)

        // ---- online softmax over this 32-key chunk ----
        float cm = st[0][0];
#pragma unroll
        for (int r = 1; r < 4; ++r) cm = fmaxf(cm, st[0][r]);
#pragma unroll
        for (int r = 0; r < 4; ++r) cm = fmaxf(cm, st[1][r]);
        cm = fmaxf(cm, __shfl_xor(cm, 16));
        cm = fmaxf(cm, __shfl_xor(cm, 32));

        const float nm    = fmaxf(m, cm);
        const float alpha = __expf(m - nm);

        float psum = 0.f;
#pragma unroll
        for (int t2 = 0; t2 < 2; ++t2)
#pragma unroll
            for (int r = 0; r < 4; ++r) {
                float p = __expf(st[t2][r] - nm);
                psum += p;
                p2[ql][t2 * 16 + g * 4 + r] = tobf(p);
            }
        psum += __shfl_xor(psum, 16);
        psum += __shfl_xor(psum, 32);

        l = l * alpha + psum;
        m = nm;
#pragma unroll
        for (int d = 0; d < 4; ++d) {
#pragma unroll
            for (int r = 0; r < 4; ++r) o[d][r] *= alpha;
        }

        // ---- PV: O^T += V^T(16d x 32k) x P^T(32k x 16q), 4 d-tiles ----
        // B fragment: B[k=key][q=ql] = p2[ql][g*8+j]  (contiguous 16B read)
        bf16x8 pb = *(const bf16x8*)(&p2[ql][g * 8]);
#pragma unroll
        for (int d = 0; d < 4; ++d) {
            bf16x8 va = *(const bf16x8*)(VT + (size_t)(d * 16 + ql) * SEQ + kb + g * 8);
            o[d] = __builtin_amdgcn_mfma_f32_16x16x32_bf16(va, pb, o[d], 0, 0, 0);
        }
    }

    const float inv = 1.f / l;
#pragma unroll
    for (int d = 0; d < 4; ++d)
#pragma unroll
        for (int r = 0; r < 4; ++r)
            Out[(size_t)(qbase + ql) * ATT + d * 16 + g * 4 + r] = o[d][r] * inv;
}

// ---------------------------------------------------------------------------
extern "C" void kernel_launch(void* const* d_in, const int* in_sizes, int n_in,
                              void* d_out, int out_size, void* d_ws, size_t ws_size,
                              hipStream_t stream)
{
    const float* X  = (const float*)d_in[0];
    const float* Wq = (const float*)d_in[1];
    const float* bq = (const float*)d_in[2];
    const float* Wk = (const float*)d_in[3];
    const float* bk = (const float*)d_in[4];
    const float* Wv = (const float*)d_in[5];
    const float* bv = (const float*)d_in[6];
    float* Out = (float*)d_out;

    __bf16* Qs = (__bf16*)d_ws;             // [SEQ][ATT], pre-scaled
    __bf16* Kb = Qs + (size_t)SEQ * ATT;    // [SEQ][ATT]
    __bf16* VT = Kb + (size_t)SEQ * ATT;    // [ATT][SEQ]

    qkv_kernel<<<SEQ / BR, 192, 0, stream>>>(X, Wq, bq, Wk, bk, Wv, bv, Qs, Kb, VT);
    flash_kernel<<<SEQ / 16, 64, 0, stream>>>(Qs, Kb, VT, Out);
}

// Round 2
// 187.782 us; speedup vs baseline: 1.2773x; 1.2773x over previous
//
#include <hip/hip_runtime.h>
#include <hip/hip_bf16.h>

#define SEQ 8192
#define EMB 512
#define ATT 64

typedef __bf16 bf16x8 __attribute__((ext_vector_type(8)));
typedef __bf16 bf16x4 __attribute__((ext_vector_type(4)));
typedef float  f32x4  __attribute__((ext_vector_type(4)));
typedef unsigned int u32x4 __attribute__((ext_vector_type(4)));
typedef unsigned int u32x2 __attribute__((ext_vector_type(2)));

static __device__ __forceinline__ unsigned int pkbf(float a, float b) {
    unsigned short ua = __builtin_bit_cast(unsigned short, (__bf16)a);
    unsigned short ub = __builtin_bit_cast(unsigned short, (__bf16)b);
    return ((unsigned int)ub << 16) | (unsigned int)ua;
}

static __device__ __forceinline__ bf16x8 cvt8(float4 a, float4 b) {
    bf16x8 r;
    r[0] = (__bf16)a.x; r[1] = (__bf16)a.y; r[2] = (__bf16)a.z; r[3] = (__bf16)a.w;
    r[4] = (__bf16)b.x; r[5] = (__bf16)b.y; r[6] = (__bf16)b.z; r[7] = (__bf16)b.w;
    return r;
}

// ---------------------------------------------------------------------------
// Kernel 1: QKV projection via bf16 MFMA.
// grid = SEQ/64 blocks, 512 threads (8 waves). Wave w: rowTile = w&3 (16 rows),
// colHalf = w>>2 (6 of the 12 col-tiles covering Q|K|V = 192 cols).
// A = X[16r x 32k] (fp32 -> bf16 in-register), B = W^T[32k x 16c].
// Outputs: Qs [SEQ][ATT] bf16 prescaled by 0.125; Kb [SEQ][ATT]; VT [ATT][SEQ].
// ---------------------------------------------------------------------------
__global__ __launch_bounds__(512) void qkv_mfma_kernel(
    const float* __restrict__ X,
    const float* __restrict__ Wq, const float* __restrict__ bq,
    const float* __restrict__ Wk, const float* __restrict__ bk,
    const float* __restrict__ Wv, const float* __restrict__ bv,
    __bf16* __restrict__ Qs, __bf16* __restrict__ Kb, __bf16* __restrict__ VT)
{
    const int lane    = threadIdx.x & 63;
    const int wv      = threadIdx.x >> 6;   // 0..7
    const int rowTile = wv & 3;
    const int colHalf = wv >> 2;            // 0..1
    const int g       = lane >> 4;          // k-group
    const int lr      = lane & 15;
    const int rowBase = blockIdx.x * 64 + rowTile * 16;

    const float* Wp[6];
    float bias[6];
#pragma unroll
    for (int ct = 0; ct < 6; ++ct) {
        const int ctg   = colHalf * 6 + ct;      // 0..11
        const int mm    = ctg >> 2;              // 0=Q 1=K 2=V
        const int colIn = (ctg & 3) * 16 + lr;
        const float* Wb = (mm == 0) ? Wq : (mm == 1) ? Wk : Wv;
        const float* bb = (mm == 0) ? bq : (mm == 1) ? bk : bv;
        Wp[ct]   = Wb + (size_t)colIn * EMB;
        bias[ct] = bb[colIn];
    }

    f32x4 acc[6] = {};
    const float* xrow = X + (size_t)(rowBase + lr) * EMB;

    for (int kb = 0; kb < EMB; kb += 32) {
        const float4 a0 = *(const float4*)(xrow + kb + g * 8);
        const float4 a1 = *(const float4*)(xrow + kb + g * 8 + 4);
        const bf16x8 af = cvt8(a0, a1);
#pragma unroll
        for (int ct = 0; ct < 6; ++ct) {
            const float4 b0 = *(const float4*)(Wp[ct] + kb + g * 8);
            const float4 b1 = *(const float4*)(Wp[ct] + kb + g * 8 + 4);
            const bf16x8 bfr = cvt8(b0, b1);
            acc[ct] = __builtin_amdgcn_mfma_f32_16x16x32_bf16(af, bfr, acc[ct], 0, 0, 0);
        }
    }

    // C layout: col = lane&15, row = rowBase + g*4 + r
#pragma unroll
    for (int ct = 0; ct < 6; ++ct) {
        const int ctg   = colHalf * 6 + ct;
        const int mm    = ctg >> 2;
        const int colIn = (ctg & 3) * 16 + lr;
        if (mm == 0) {
#pragma unroll
            for (int r = 0; r < 4; ++r)
                Qs[(size_t)(rowBase + g * 4 + r) * ATT + colIn] =
                    (__bf16)((acc[ct][r] + bias[ct]) * 0.125f);
        } else if (mm == 1) {
#pragma unroll
            for (int r = 0; r < 4; ++r)
                Kb[(size_t)(rowBase + g * 4 + r) * ATT + colIn] =
                    (__bf16)(acc[ct][r] + bias[ct]);
        } else {
            bf16x4 v4;
#pragma unroll
            for (int r = 0; r < 4; ++r) v4[r] = (__bf16)(acc[ct][r] + bias[ct]);
            *(bf16x4*)(VT + (size_t)colIn * SEQ + rowBase + g * 4) = v4;
        }
    }
}

// ---------------------------------------------------------------------------
// Kernel 2: flash attention with split-K over the key sequence.
// grid = (SEQ/16, nsplit), one wave per block, 16 q-rows per wave.
// Swapped QK^T (scores^T) so q = lane&15; softmax row-reduce = 2 shfl_xor.
// P packed to bf16 dwords in-register, routed via XOR-swizzled LDS
// (2x ds_write_b64 + 1x ds_read_b128). O^T = V^T x P^T.
// nsplit==1: write normalized Out. Else: write unnormalized partial + (m,l).
// ---------------------------------------------------------------------------
__global__ __launch_bounds__(64) void flash_kernel(
    const __bf16* __restrict__ Qs,
    const __bf16* __restrict__ Kb,
    const __bf16* __restrict__ VT,
    float* __restrict__ Out,
    float* __restrict__ Opart,
    float2* __restrict__ Ml,
    int nsplit)
{
    __shared__ unsigned int pdw[16][20];   // [q][16 dwords + pad], XOR-swizzled

    const int lane  = threadIdx.x;
    const int g     = lane >> 4;
    const int ql    = lane & 15;
    const int qbase = blockIdx.x * 16;
    const int s     = blockIdx.y;
    const int KS    = SEQ / nsplit;
    const int k0    = s * KS, k1 = k0 + KS;
    const int xk    = (ql & 3) << 2;       // XOR swizzle for LDS dword col
    unsigned int* prow = &pdw[ql][0];

    const bf16x8 qf0 = *(const bf16x8*)(Qs + (size_t)(qbase + ql) * ATT + g * 8);
    const bf16x8 qf1 = *(const bf16x8*)(Qs + (size_t)(qbase + ql) * ATT + 32 + g * 8);

    float m = -1e30f, l = 0.f;
    f32x4 o[4] = {};                        // O^T: d = dt*16 + g*4 + r, q = ql

    for (int kb = k0; kb < k1; kb += 32) {
        // ---- QK^T (swapped): scores^T, already scaled (Qs prescaled) ----
        f32x4 st[2];
        st[0] = f32x4{0.f, 0.f, 0.f, 0.f};
        st[1] = f32x4{0.f, 0.f, 0.f, 0.f};
#pragma unroll
        for (int t2 = 0; t2 < 2; ++t2) {
            const __bf16* kp = Kb + (size_t)(kb + t2 * 16 + ql) * ATT + g * 8;
            bf16x8 ka0 = *(const bf16x8*)(kp);
            bf16x8 ka1 = *(const bf16x8*)(kp + 32);
            st[t2] = __builtin_amdgcn_mfma_f32_16x16x32_bf16(ka0, qf0, st[t2], 0, 0, 0);
            st[t2] = __builtin_amdgcn_mfma_f32_16x16x32_bf16(ka1, qf1, st[t2], 0, 0, 0);
        }
        // st[t2][r] = S^T[key = kb + t2*16 + g*4 + r][q = ql]

        // ---- online softmax ----
        float cm = st[0][0];
#pragma unroll
        for (int r = 1; r < 4; ++r) cm = fmaxf(cm, st[0][r]);
#pragma unroll
        for (int r = 0; r < 4; ++r) cm = fmaxf(cm, st[1][r]);
        cm = fmaxf(cm, __shfl_xor(cm, 16));
        cm = fmaxf(cm, __shfl_xor(cm, 32));

        const float nm    = fmaxf(m, cm);
        const float alpha = __expf(m - nm);

        float psum = 0.f;
#pragma unroll
        for (int t2 = 0; t2 < 2; ++t2) {
            float p0 = __expf(st[t2][0] - nm);
            float p1 = __expf(st[t2][1] - nm);
            float p2 = __expf(st[t2][2] - nm);
            float p3 = __expf(st[t2][3] - nm);
            psum += (p0 + p1) + (p2 + p3);
            u32x2 w;
            w[0] = pkbf(p0, p1);
            w[1] = pkbf(p2, p3);
            // logical dword col = t2*8 + g*2 (+1), stored at col ^ xk
            *(u32x2*)(prow + ((t2 * 8 + g * 2) ^ xk)) = w;
        }
        psum += __shfl_xor(psum, 16);
        psum += __shfl_xor(psum, 32);

        l = l * alpha + psum;
        m = nm;
#pragma unroll
        for (int dt = 0; dt < 4; ++dt)
#pragma unroll
            for (int r = 0; r < 4; ++r) o[dt][r] *= alpha;

        // ---- PV: B fragment = keys g*8..g*8+7 for col ql ----
        const u32x4 pw = *(const u32x4*)(prow + ((g * 4) ^ xk));
        const bf16x8 pb = __builtin_bit_cast(bf16x8, pw);
#pragma unroll
        for (int dt = 0; dt < 4; ++dt) {
            bf16x8 va = *(const bf16x8*)(VT + (size_t)(dt * 16 + ql) * SEQ + kb + g * 8);
            o[dt] = __builtin_amdgcn_mfma_f32_16x16x32_bf16(va, pb, o[dt], 0, 0, 0);
        }
    }

    if (nsplit == 1) {
        const float inv = 1.f / l;
#pragma unroll
        for (int dt = 0; dt < 4; ++dt)
#pragma unroll
            for (int r = 0; r < 4; ++r)
                Out[(size_t)(qbase + ql) * ATT + dt * 16 + g * 4 + r] = o[dt][r] * inv;
    } else {
        float* op = Opart + ((size_t)s * SEQ + qbase + ql) * ATT;
#pragma unroll
        for (int dt = 0; dt < 4; ++dt)
            *(f32x4*)(op + dt * 16 + g * 4) = o[dt];
        if (g == 0)
            Ml[(size_t)s * SEQ + qbase + ql] = make_float2(m, l);
    }
}

// ---------------------------------------------------------------------------
// Kernel 3: combine split-K partials.
// grid = SEQ/64, 256 threads: thread -> (q = bid*64 + t/4, dg = t&3 -> 16 d's).
// ---------------------------------------------------------------------------
__global__ __launch_bounds__(256) void combine_kernel(
    const float* __restrict__ Opart,
    const float2* __restrict__ Ml,
    float* __restrict__ Out,
    int nsplit)
{
    const int t  = threadIdx.x;
    const int q  = blockIdx.x * 64 + (t >> 2);
    const int dg = t & 3;

    float M = -1e30f;
    for (int s = 0; s < nsplit; ++s)
        M = fmaxf(M, Ml[(size_t)s * SEQ + q].x);

    float den = 0.f;
    f32x4 acc[4] = {};
    for (int s = 0; s < nsplit; ++s) {
        const float2 ml = Ml[(size_t)s * SEQ + q];
        const float  w  = __expf(ml.x - M);
        den += w * ml.y;
        const float* op = Opart + ((size_t)s * SEQ + q) * ATT + dg * 16;
#pragma unroll
        for (int j = 0; j < 4; ++j) {
            const f32x4 v = *(const f32x4*)(op + j * 4);
            acc[j] += v * w;
        }
    }
    const float inv = 1.f / den;
#pragma unroll
    for (int j = 0; j < 4; ++j)
        *(f32x4*)(Out + (size_t)q * ATT + dg * 16 + j * 4) = acc[j] * inv;
}

// ---------------------------------------------------------------------------
extern "C" void kernel_launch(void* const* d_in, const int* in_sizes, int n_in,
                              void* d_out, int out_size, void* d_ws, size_t ws_size,
                              hipStream_t stream)
{
    const float* X  = (const float*)d_in[0];
    const float* Wq = (const float*)d_in[1];
    const float* bq = (const float*)d_in[2];
    const float* Wk = (const float*)d_in[3];
    const float* bk = (const float*)d_in[4];
    const float* Wv = (const float*)d_in[5];
    const float* bv = (const float*)d_in[6];
    float* Out = (float*)d_out;

    __bf16* Qs = (__bf16*)d_ws;                 // [SEQ][ATT] prescaled
    __bf16* Kb = Qs + (size_t)SEQ * ATT;        // [SEQ][ATT]
    __bf16* VT = Kb + (size_t)SEQ * ATT;        // [ATT][SEQ]

    const size_t base = (size_t)3 * SEQ * ATT * 2;                 // 3 MB
    const size_t per  = (size_t)SEQ * ATT * 4 + (size_t)SEQ * 8;   // Opart + Ml per split

    int nsplit = 1;
    const int cands[4] = {16, 8, 4, 2};
    for (int i = 0; i < 4; ++i) {
        if (base + (size_t)cands[i] * per <= ws_size) { nsplit = cands[i]; break; }
    }

    float*  Opart = (float*)((char*)d_ws + base);
    float2* Ml    = (float2*)((char*)d_ws + base + (size_t)nsplit * SEQ * ATT * 4);

    qkv_mfma_kernel<<<SEQ / 64, 512, 0, stream>>>(X, Wq, bq, Wk, bk, Wv, bv, Qs, Kb, VT);

    dim3 fgrid(SEQ / 16, nsplit);
    flash_kernel<<<fgrid, 64, 0, stream>>>(Qs, Kb, VT, Out, Opart, Ml, nsplit);

    if (nsplit > 1)
        combine_kernel<<<SEQ / 64, 256, 0, stream>>>(Opart, Ml, Out, nsplit);
}

// Round 3
// 85.878 us; speedup vs baseline: 2.7930x; 2.1866x over previous
//
#include <hip/hip_runtime.h>
#include <hip/hip_bf16.h>

#define SEQ 8192
#define EMB 512
#define ATT 64
#define SCALE 0.18033688f   // 0.125 * log2(e): QK^T lands in log2 domain

typedef __bf16 bf16x8 __attribute__((ext_vector_type(8)));
typedef __bf16 bf16x4 __attribute__((ext_vector_type(4)));
typedef float  f32x4  __attribute__((ext_vector_type(4)));
typedef unsigned int u32x4 __attribute__((ext_vector_type(4)));
typedef unsigned int u32x2 __attribute__((ext_vector_type(2)));

static __device__ __forceinline__ unsigned int pkbf(float a, float b) {
    unsigned short ua = __builtin_bit_cast(unsigned short, (__bf16)a);
    unsigned short ub = __builtin_bit_cast(unsigned short, (__bf16)b);
    return ((unsigned int)ub << 16) | (unsigned int)ua;
}
static __device__ __forceinline__ bf16x8 cvt8(float4 a, float4 b) {
    bf16x8 r;
    r[0] = (__bf16)a.x; r[1] = (__bf16)a.y; r[2] = (__bf16)a.z; r[3] = (__bf16)a.w;
    r[4] = (__bf16)b.x; r[5] = (__bf16)b.y; r[6] = (__bf16)b.z; r[7] = (__bf16)b.w;
    return r;
}
// async global->LDS, 16B per lane; dst is wave-uniform base + lane*16
static __device__ __forceinline__ void gll16(const void* g, void* l) {
    __builtin_amdgcn_global_load_lds(
        (const __attribute__((address_space(1))) unsigned int*)g,
        (__attribute__((address_space(3))) unsigned int*)l, 16, 0, 0);
}

// ---------------------------------------------------------------------------
// Kernel A: convert X -> Xb (bf16) and W/b -> Wb[192][512]/bb[192]
// (rows 0-63 = Wq prescaled by SCALE, 64-127 = Wk, 128-191 = Wv).
// ---------------------------------------------------------------------------
__global__ __launch_bounds__(256) void convert_kernel(
    const float* __restrict__ X,
    const float* __restrict__ Wq, const float* __restrict__ bq,
    const float* __restrict__ Wk, const float* __restrict__ bk,
    const float* __restrict__ Wv, const float* __restrict__ bv,
    __bf16* __restrict__ Xb, __bf16* __restrict__ Wb, float* __restrict__ bb)
{
    const int bid = blockIdx.x, tid = threadIdx.x;
    if (bid < 2048) {                                   // X: 4M elems
        const size_t e = (size_t)bid * 2048 + (size_t)tid * 8;
        const float4 a0 = *(const float4*)(X + e);
        const float4 a1 = *(const float4*)(X + e + 4);
        *(bf16x8*)(Xb + e) = cvt8(a0, a1);
    } else if (bid < 2096) {                            // W: 98304 elems
        const int e  = (bid - 2048) * 2048 + tid * 8;
        const int mm = e >> 15;                         // 32768 per matrix
        const int wi = e & 32767;
        const float* Ws = mm == 0 ? Wq : (mm == 1 ? Wk : Wv);
        const float  s  = mm == 0 ? SCALE : 1.0f;
        float4 a0 = *(const float4*)(Ws + wi);
        float4 a1 = *(const float4*)(Ws + wi + 4);
        a0.x *= s; a0.y *= s; a0.z *= s; a0.w *= s;
        a1.x *= s; a1.y *= s; a1.z *= s; a1.w *= s;
        *(bf16x8*)(Wb + e) = cvt8(a0, a1);
    } else if (tid < 192) {                             // biases
        const int mm = tid >> 6, c = tid & 63;
        const float* bs = mm == 0 ? bq : (mm == 1 ? bk : bv);
        bb[tid] = bs[c] * (mm == 0 ? SCALE : 1.0f);
    }
}

// ---------------------------------------------------------------------------
// Kernel B: QKV projection, pure bf16 MFMA.
// grid = SEQ/16 blocks x 256 thr (4 waves). Block owns one 16-row tile;
// wave wv owns col-tiles wv*3 .. wv*3+2 of [Q0..3 K0..3 V0..3].
// ---------------------------------------------------------------------------
__global__ __launch_bounds__(256) void qkv_kernel(
    const __bf16* __restrict__ Xb, const __bf16* __restrict__ Wb,
    const float* __restrict__ bb,
    __bf16* __restrict__ Qs, __bf16* __restrict__ Kb, __bf16* __restrict__ VT)
{
    const int lane = threadIdx.x & 63, wv = threadIdx.x >> 6;
    const int g = lane >> 4, lr = lane & 15;
    const int rowBase = blockIdx.x * 16;
    const int tt0 = wv * 3;

    const __bf16* xrow = Xb + (size_t)(rowBase + lr) * EMB;
    const __bf16* wrow[3];
    float bias[3];
#pragma unroll
    for (int j = 0; j < 3; ++j) {
        wrow[j] = Wb + (size_t)((tt0 + j) * 16 + lr) * EMB;
        bias[j] = bb[(tt0 + j) * 16 + lr];
    }

    f32x4 acc[3] = {};
    for (int kb = 0; kb < EMB; kb += 32) {
        const bf16x8 af = *(const bf16x8*)(xrow + kb + g * 8);
#pragma unroll
        for (int j = 0; j < 3; ++j) {
            const bf16x8 bf = *(const bf16x8*)(wrow[j] + kb + g * 8);
            acc[j] = __builtin_amdgcn_mfma_f32_16x16x32_bf16(af, bf, acc[j], 0, 0, 0);
        }
    }
    // C layout: col = lr, row = rowBase + g*4 + r (validated r1/r2)
#pragma unroll
    for (int j = 0; j < 3; ++j) {
        const int tt = tt0 + j, mm = tt >> 2, col = (tt & 3) * 16 + lr;
        if (mm == 0) {
#pragma unroll
            for (int r = 0; r < 4; ++r)
                Qs[(size_t)(rowBase + g * 4 + r) * ATT + col] = (__bf16)(acc[j][r] + bias[j]);
        } else if (mm == 1) {
#pragma unroll
            for (int r = 0; r < 4; ++r)
                Kb[(size_t)(rowBase + g * 4 + r) * ATT + col] = (__bf16)(acc[j][r] + bias[j]);
        } else {
            bf16x4 v4;
#pragma unroll
            for (int r = 0; r < 4; ++r) v4[r] = (__bf16)(acc[j][r] + bias[j]);
            *(bf16x4*)(VT + (size_t)col * SEQ + rowBase + g * 4) = v4;
        }
    }
}

// ---------------------------------------------------------------------------
// Kernel C: flash attention, 4 waves/block, KVBLK=32, split-K over keys.
// Double-buffered LDS K/V staged with global_load_lds (shared by 4 waves).
// K tile source-preswizzled so ds_read_b128 A-frags are conflict-optimal.
// log2-domain softmax + defer-max (THR = 8*log2e ~ 11.5).
// ---------------------------------------------------------------------------
__global__ __launch_bounds__(256, 8) void flash_kernel(
    const __bf16* __restrict__ Qs,
    const __bf16* __restrict__ Kb,
    const __bf16* __restrict__ VT,
    float* __restrict__ Out,
    float* __restrict__ Opart,
    float2* __restrict__ Ml,
    int nsplit)
{
    __shared__ __bf16 Kt[2][32][64];        // row=key, phys slot s holds d-slot s^(row&7)
    __shared__ __bf16 Vt[2][64][32];        // row=d, keys linear (64B rows: naturally optimal)
    __shared__ unsigned int pdw[4][16][16]; // per-wave P rows (64B rows: naturally optimal)

    const int lane = threadIdx.x & 63, wv = threadIdx.x >> 6;
    const int g = lane >> 4, ql = lane & 15;
    const int qbase = blockIdx.x * 64 + wv * 16;
    const int s  = blockIdx.y;
    const int KS = SEQ / nsplit;
    const int k0 = s * KS;
    const int nt = KS / 32;

    // per-lane stage source offsets (constant across iterations)
    const int    kSrc = (wv * 8 + (lane >> 3)) * ATT + (((lane & 7) ^ (lane >> 3)) << 3);
    const size_t vSrc = (size_t)(wv * 16 + (lane >> 2)) * SEQ + ((lane & 3) << 3);

    const bf16x8 qf0 = *(const bf16x8*)(Qs + (size_t)(qbase + ql) * ATT + g * 8);
    const bf16x8 qf1 = *(const bf16x8*)(Qs + (size_t)(qbase + ql) * ATT + 32 + g * 8);

    float m = -1e30f, l = 0.f;
    f32x4 o[4] = {};

    // prologue: stage tile 0 into buf 0 (each wave: 1 K chunk + 1 V chunk)
    gll16(Kb + (size_t)k0 * ATT + kSrc, &Kt[0][wv * 8][0]);
    gll16(VT + vSrc + k0,              &Vt[0][wv * 16][0]);

    int cur = 0;
    for (int t = 0; t < nt; ++t) {
        __syncthreads();   // drains vmcnt: buf[cur] staged & visible
        if (t + 1 < nt) {  // issue next tile's stage; lands during compute
            const int kb = k0 + (t + 1) * 32;
            gll16(Kb + (size_t)kb * ATT + kSrc, &Kt[cur ^ 1][wv * 8][0]);
            gll16(VT + vSrc + kb,              &Vt[cur ^ 1][wv * 16][0]);
        }

        // ---- QK^T (swapped): scores^T in log2 domain ----
        f32x4 st[2];
        st[0] = f32x4{0.f, 0.f, 0.f, 0.f};
        st[1] = f32x4{0.f, 0.f, 0.f, 0.f};
#pragma unroll
        for (int t2 = 0; t2 < 2; ++t2) {
            const int r = t2 * 16 + ql;
            const bf16x8 ka0 = *(const bf16x8*)&Kt[cur][r][(g ^ (ql & 7)) << 3];
            const bf16x8 ka1 = *(const bf16x8*)&Kt[cur][r][((g + 4) ^ (ql & 7)) << 3];
            st[t2] = __builtin_amdgcn_mfma_f32_16x16x32_bf16(ka0, qf0, st[t2], 0, 0, 0);
            st[t2] = __builtin_amdgcn_mfma_f32_16x16x32_bf16(ka1, qf1, st[t2], 0, 0, 0);
        }

        // ---- online softmax, defer-max ----
        float cm = fmaxf(fmaxf(fmaxf(st[0][0], st[0][1]), fmaxf(st[0][2], st[0][3])),
                         fmaxf(fmaxf(st[1][0], st[1][1]), fmaxf(st[1][2], st[1][3])));
        cm = fmaxf(cm, __shfl_xor(cm, 16));
        cm = fmaxf(cm, __shfl_xor(cm, 32));
        if (__any(cm > m + 11.5f)) {
            const float nm    = fmaxf(m, cm);
            const float alpha = __builtin_amdgcn_exp2f(m - nm);
            l *= alpha;
#pragma unroll
            for (int dt = 0; dt < 4; ++dt)
#pragma unroll
                for (int r = 0; r < 4; ++r) o[dt][r] *= alpha;
            m = nm;
        }

        float psum = 0.f;
        unsigned int* prow = &pdw[wv][ql][0];
#pragma unroll
        for (int t2 = 0; t2 < 2; ++t2) {
            const float p0 = __builtin_amdgcn_exp2f(st[t2][0] - m);
            const float p1 = __builtin_amdgcn_exp2f(st[t2][1] - m);
            const float p2 = __builtin_amdgcn_exp2f(st[t2][2] - m);
            const float p3 = __builtin_amdgcn_exp2f(st[t2][3] - m);
            psum += (p0 + p1) + (p2 + p3);
            u32x2 w;
            w[0] = pkbf(p0, p1);
            w[1] = pkbf(p2, p3);
            *(u32x2*)(prow + t2 * 8 + g * 2) = w;
        }
        psum += __shfl_xor(psum, 16);
        psum += __shfl_xor(psum, 32);
        l += psum;

        // ---- PV: O^T += V^T x P^T ----
        const u32x4 pw = *(const u32x4*)(prow + g * 4);
        const bf16x8 pb = __builtin_bit_cast(bf16x8, pw);
#pragma unroll
        for (int dt = 0; dt < 4; ++dt) {
            const bf16x8 va = *(const bf16x8*)&Vt[cur][dt * 16 + ql][g * 8];
            o[dt] = __builtin_amdgcn_mfma_f32_16x16x32_bf16(va, pb, o[dt], 0, 0, 0);
        }

        __syncthreads();   // all waves done reading buf[cur] before overwrite
        cur ^= 1;
    }

    if (nsplit == 1) {
        const float inv = 1.f / l;
#pragma unroll
        for (int dt = 0; dt < 4; ++dt)
#pragma unroll
            for (int r = 0; r < 4; ++r)
                Out[(size_t)(qbase + ql) * ATT + dt * 16 + g * 4 + r] = o[dt][r] * inv;
    } else {
        float* op = Opart + ((size_t)s * SEQ + qbase + ql) * ATT;
#pragma unroll
        for (int dt = 0; dt < 4; ++dt)
            *(f32x4*)(op + dt * 16 + g * 4) = o[dt];
        if (g == 0)
            Ml[(size_t)s * SEQ + qbase + ql] = make_float2(m, l);
    }
}

// ---------------------------------------------------------------------------
// Kernel D: combine split-K partials (log2-domain m).
// ---------------------------------------------------------------------------
__global__ __launch_bounds__(256) void combine_kernel(
    const float* __restrict__ Opart,
    const float2* __restrict__ Ml,
    float* __restrict__ Out,
    int nsplit)
{
    const int t  = threadIdx.x;
    const int q  = blockIdx.x * 64 + (t >> 2);
    const int dg = t & 3;

    float M = -1e30f;
    for (int s = 0; s < nsplit; ++s)
        M = fmaxf(M, Ml[(size_t)s * SEQ + q].x);

    float den = 0.f;
    f32x4 acc[4] = {};
    for (int s = 0; s < nsplit; ++s) {
        const float2 ml = Ml[(size_t)s * SEQ + q];
        const float  w  = __builtin_amdgcn_exp2f(ml.x - M);
        den += w * ml.y;
        const float* op = Opart + ((size_t)s * SEQ + q) * ATT + dg * 16;
#pragma unroll
        for (int j = 0; j < 4; ++j) {
            const f32x4 v = *(const f32x4*)(op + j * 4);
            acc[j] += v * w;
        }
    }
    const float inv = 1.f / den;
#pragma unroll
    for (int j = 0; j < 4; ++j)
        *(f32x4*)(Out + (size_t)q * ATT + dg * 16 + j * 4) = acc[j] * inv;
}

// ---------------------------------------------------------------------------
extern "C" void kernel_launch(void* const* d_in, const int* in_sizes, int n_in,
                              void* d_out, int out_size, void* d_ws, size_t ws_size,
                              hipStream_t stream)
{
    const float* X  = (const float*)d_in[0];
    const float* Wq = (const float*)d_in[1];
    const float* bq = (const float*)d_in[2];
    const float* Wk = (const float*)d_in[3];
    const float* bk = (const float*)d_in[4];
    const float* Wv = (const float*)d_in[5];
    const float* bv = (const float*)d_in[6];
    float* Out = (float*)d_out;

    char* ws = (char*)d_ws;
    const size_t offQs = 0;
    const size_t offKb = offQs + (size_t)SEQ * ATT * 2;
    const size_t offVT = offKb + (size_t)SEQ * ATT * 2;
    const size_t offXb = offVT + (size_t)SEQ * ATT * 2;
    const size_t offWb = offXb + (size_t)SEQ * EMB * 2;
    const size_t offbb = offWb + (size_t)192 * EMB * 2;
    const size_t base  = offbb + 1024;

    __bf16* Qs = (__bf16*)(ws + offQs);
    __bf16* Kb = (__bf16*)(ws + offKb);
    __bf16* VT = (__bf16*)(ws + offVT);
    __bf16* Xb = (__bf16*)(ws + offXb);
    __bf16* Wb = (__bf16*)(ws + offWb);
    float*  bb = (float*)(ws + offbb);

    const size_t per = (size_t)SEQ * ATT * 4 + (size_t)SEQ * 8;
    int nsplit = 1;
    const int cands[4] = {16, 8, 4, 2};
    for (int i = 0; i < 4; ++i)
        if (base + (size_t)cands[i] * per <= ws_size) { nsplit = cands[i]; break; }

    float*  Opart = (float*)(ws + base);
    float2* Ml    = (float2*)(ws + base + (size_t)nsplit * SEQ * ATT * 4);

    convert_kernel<<<2097, 256, 0, stream>>>(X, Wq, bq, Wk, bk, Wv, bv, Xb, Wb, bb);
    qkv_kernel<<<SEQ / 16, 256, 0, stream>>>(Xb, Wb, bb, Qs, Kb, VT);

    dim3 fgrid(SEQ / 64, nsplit);
    flash_kernel<<<fgrid, 256, 0, stream>>>(Qs, Kb, VT, Out, Opart, Ml, nsplit);

    if (nsplit > 1)
        combine_kernel<<<SEQ / 64, 256, 0, stream>>>(Opart, Ml, Out, nsplit);
}

// Round 4
// 75.550 us; speedup vs baseline: 3.1748x; 1.1367x over previous
//
#include <hip/hip_runtime.h>
#include <hip/hip_bf16.h>

#define SEQ 8192
#define EMB 512
#define ATT 64
#define SCALE 0.18033688f   // 0.125 * log2(e): scores land in log2 domain

typedef __bf16 bf16x8 __attribute__((ext_vector_type(8)));
typedef __bf16 bf16x4 __attribute__((ext_vector_type(4)));
typedef float  f32x4  __attribute__((ext_vector_type(4)));
typedef float  f32x16 __attribute__((ext_vector_type(16)));
typedef unsigned int u32x4 __attribute__((ext_vector_type(4)));

static __device__ __forceinline__ unsigned int pkbf(float a, float b) {
    unsigned short ua = __builtin_bit_cast(unsigned short, (__bf16)a);
    unsigned short ub = __builtin_bit_cast(unsigned short, (__bf16)b);
    return ((unsigned int)ub << 16) | (unsigned int)ua;
}
static __device__ __forceinline__ bf16x8 cvt8(float4 a, float4 b) {
    bf16x8 r;
    r[0] = (__bf16)a.x; r[1] = (__bf16)a.y; r[2] = (__bf16)a.z; r[3] = (__bf16)a.w;
    r[4] = (__bf16)b.x; r[5] = (__bf16)b.y; r[6] = (__bf16)b.z; r[7] = (__bf16)b.w;
    return r;
}
static __device__ __forceinline__ void gll16(const void* g, void* l) {
    __builtin_amdgcn_global_load_lds(
        (const __attribute__((address_space(1))) unsigned int*)g,
        (__attribute__((address_space(3))) unsigned int*)l, 16, 0, 0);
}
// v_permlane32_swap_b32: a' = {a_lo | b_lo(in hi lanes)}, b' = {a_hi(in lo lanes) | b_hi}
static __device__ __forceinline__ void plswap(unsigned int& a, unsigned int& b) {
    asm("v_permlane32_swap_b32 %0, %1" : "+v"(a), "+v"(b));
}

// ---------------------------------------------------------------------------
// Kernel A: convert W/b only -> Wb[192][512] bf16 (Wq rows prescaled), bb[192]
// ---------------------------------------------------------------------------
__global__ __launch_bounds__(256) void convertw_kernel(
    const float* __restrict__ Wq, const float* __restrict__ bq,
    const float* __restrict__ Wk, const float* __restrict__ bk,
    const float* __restrict__ Wv, const float* __restrict__ bv,
    __bf16* __restrict__ Wb, float* __restrict__ bb)
{
    const int bid = blockIdx.x, tid = threadIdx.x;
    if (bid < 48) {
        const int e  = bid * 2048 + tid * 8;
        const int mm = e >> 15;
        const int wi = e & 32767;
        const float* Ws = mm == 0 ? Wq : (mm == 1 ? Wk : Wv);
        const float  s  = mm == 0 ? SCALE : 1.0f;
        float4 a0 = *(const float4*)(Ws + wi);
        float4 a1 = *(const float4*)(Ws + wi + 4);
        a0.x *= s; a0.y *= s; a0.z *= s; a0.w *= s;
        a1.x *= s; a1.y *= s; a1.z *= s; a1.w *= s;
        *(bf16x8*)(Wb + e) = cvt8(a0, a1);
    } else if (tid < 192) {
        const int mm = tid >> 6, c = tid & 63;
        const float* bs = mm == 0 ? bq : (mm == 1 ? bk : bv);
        bb[tid] = bs[c] * (mm == 0 ? SCALE : 1.0f);
    }
}

// ---------------------------------------------------------------------------
// Kernel B: QKV projection (bf16 MFMA, X read fp32 + in-register convert).
// grid = SEQ/16, 256 thr (4 waves); wave wv owns col-tiles wv*3..wv*3+2.
// ---------------------------------------------------------------------------
__global__ __launch_bounds__(256) void qkv_kernel(
    const float* __restrict__ X, const __bf16* __restrict__ Wb,
    const float* __restrict__ bb,
    __bf16* __restrict__ Qs, __bf16* __restrict__ Kb, __bf16* __restrict__ VT)
{
    const int lane = threadIdx.x & 63, wv = threadIdx.x >> 6;
    const int g = lane >> 4, lr = lane & 15;
    const int rowBase = blockIdx.x * 16;
    const int tt0 = wv * 3;

    const float* xrow = X + (size_t)(rowBase + lr) * EMB;
    const __bf16* wrow[3];
    float bias[3];
#pragma unroll
    for (int j = 0; j < 3; ++j) {
        wrow[j] = Wb + (size_t)((tt0 + j) * 16 + lr) * EMB;
        bias[j] = bb[(tt0 + j) * 16 + lr];
    }

    f32x4 acc[3] = {};
    for (int kb = 0; kb < EMB; kb += 32) {
        const float4 x0 = *(const float4*)(xrow + kb + g * 8);
        const float4 x1 = *(const float4*)(xrow + kb + g * 8 + 4);
        const bf16x8 af = cvt8(x0, x1);
#pragma unroll
        for (int j = 0; j < 3; ++j) {
            const bf16x8 bf = *(const bf16x8*)(wrow[j] + kb + g * 8);
            acc[j] = __builtin_amdgcn_mfma_f32_16x16x32_bf16(af, bf, acc[j], 0, 0, 0);
        }
    }
#pragma unroll
    for (int j = 0; j < 3; ++j) {
        const int tt = tt0 + j, mm = tt >> 2, col = (tt & 3) * 16 + lr;
        if (mm == 0) {
#pragma unroll
            for (int r = 0; r < 4; ++r)
                Qs[(size_t)(rowBase + g * 4 + r) * ATT + col] = (__bf16)(acc[j][r] + bias[j]);
        } else if (mm == 1) {
#pragma unroll
            for (int r = 0; r < 4; ++r)
                Kb[(size_t)(rowBase + g * 4 + r) * ATT + col] = (__bf16)(acc[j][r] + bias[j]);
        } else {
            bf16x4 v4;
#pragma unroll
            for (int r = 0; r < 4; ++r) v4[r] = (__bf16)(acc[j][r] + bias[j]);
            *(bf16x4*)(VT + (size_t)col * SEQ + rowBase + g * 4) = v4;
        }
    }
}

// ---------------------------------------------------------------------------
// Kernel C: flash attention, 32x32x16 MFMA, QBLK=32/wave, 4 waves (128 q/blk).
// Swapped QK^T -> S^T[key][q], q = lane&31; softmax in-register (tree +
// shfl_xor(32)); P routed to PV B-frags via pack + 2x v_permlane32_swap per
// k-step (no P LDS). K/V double-buffered in LDS via global_load_lds with
// conflict-free XOR swizzles (K: slot^(row&7), V: slot^((d>>1)&3)).
// ---------------------------------------------------------------------------
__global__ __launch_bounds__(256, 4) void flash_kernel(
    const __bf16* __restrict__ Qs,
    const __bf16* __restrict__ Kb,
    const __bf16* __restrict__ VT,
    float* __restrict__ Out,
    float* __restrict__ Opart,
    float2* __restrict__ Ml,
    int nsplit)
{
    __shared__ __bf16 Kt[2][32][64];   // phys 16B-slot s of row r holds d-chunk s^(r&7)
    __shared__ __bf16 Vt[2][64][32];   // phys slot s of row d holds key-chunk s^((d>>1)&3)

    const int l   = threadIdx.x & 63;
    const int wv  = threadIdx.x >> 6;
    const int q32 = l & 31;            // q col within wave tile; also K/V row index
    const int hi  = l >> 5;
    const int q   = blockIdx.x * 128 + wv * 32 + q32;
    const int s   = blockIdx.y;
    const int KS  = SEQ / nsplit;
    const int k0  = s * KS;
    const int nt  = KS / 32;

    // staging source offsets (source-preswizzled; LDS dest is linear lane*16)
    const int    kSrc = (wv * 8 + (l >> 3)) * ATT + (((l & 7) ^ (l >> 3)) << 3);
    const size_t vSrc = (size_t)(wv * 16 + (l >> 2)) * SEQ + (((l & 3) ^ ((l >> 3) & 3)) << 3);

    // Q fragments: B[k = dk*16 + hi*8 + j][col = q]
    bf16x8 qf[4];
#pragma unroll
    for (int dk = 0; dk < 4; ++dk)
        qf[dk] = *(const bf16x8*)(Qs + (size_t)q * ATT + dk * 16 + hi * 8);

    float m = -1e30f, lsum = 0.f;
    f32x16 o0 = {}, o1 = {};

    gll16(Kb + (size_t)k0 * ATT + kSrc, &Kt[0][wv * 8][0]);
    gll16(VT + vSrc + k0,               &Vt[0][wv * 16][0]);

    int cur = 0;
    for (int t = 0; t < nt; ++t) {
        __syncthreads();               // buf[cur] staged (vmcnt drained) + prev reads done
        if (t + 1 < nt) {
            const int kb = k0 + (t + 1) * 32;
            gll16(Kb + (size_t)kb * ATT + kSrc, &Kt[cur ^ 1][wv * 8][0]);
            gll16(VT + vSrc + kb,               &Vt[cur ^ 1][wv * 16][0]);
        }

        // ---- QK^T: S^T[key][q] accumulate over 4 d-chunks of 16 ----
        f32x16 st = {};
        const __bf16* ktile = &Kt[cur][0][0];
#pragma unroll
        for (int dk = 0; dk < 4; ++dk) {
            const int phys = (dk * 2 + hi) ^ (q32 & 7);
            const bf16x8 ka = *(const bf16x8*)(ktile + q32 * 64 + phys * 8);
            st = __builtin_amdgcn_mfma_f32_32x32x16_bf16(ka, qf[dk], st, 0, 0, 0);
        }
        // st[reg] = S^T[key = (reg&3) + 8*(reg>>2) + 4*hi][q]  (log2 domain)

        // ---- online softmax (defer-max, THR = 8*log2e ~ 11.5) ----
        float m0 = fmaxf(fmaxf(st[0], st[1]), fmaxf(st[2], st[3]));
        float m1 = fmaxf(fmaxf(st[4], st[5]), fmaxf(st[6], st[7]));
        float m2 = fmaxf(fmaxf(st[8], st[9]), fmaxf(st[10], st[11]));
        float m3 = fmaxf(fmaxf(st[12], st[13]), fmaxf(st[14], st[15]));
        float cm = fmaxf(fmaxf(m0, m1), fmaxf(m2, m3));
        cm = fmaxf(cm, __shfl_xor(cm, 32));
        if (__any(cm > m + 11.5f)) {
            const float nm = fmaxf(m, cm);
            const float al = __builtin_amdgcn_exp2f(m - nm);
            lsum *= al;
#pragma unroll
            for (int r = 0; r < 16; ++r) { o0[r] *= al; o1[r] *= al; }
            m = nm;
        }

#pragma unroll
        for (int r = 0; r < 16; ++r) st[r] = __builtin_amdgcn_exp2f(st[r] - m);
        float ps = (((st[0] + st[1]) + (st[2] + st[3])) + ((st[4] + st[5]) + (st[6] + st[7]))) +
                   (((st[8] + st[9]) + (st[10] + st[11])) + ((st[12] + st[13]) + (st[14] + st[15])));
        ps += __shfl_xor(ps, 32);
        lsum += ps;

        // pack quads: quad i = regs 4i..4i+3 (keys 8i+0..3 + 4*hi)
        unsigned int c0[4], c1[4];
#pragma unroll
        for (int i = 0; i < 4; ++i) {
            c0[i] = pkbf(st[4 * i],     st[4 * i + 1]);
            c1[i] = pkbf(st[4 * i + 2], st[4 * i + 3]);
        }

        // ---- PV: O^T += V^T x P^T, 2 k-steps x 2 d-tiles ----
        const __bf16* vtile = &Vt[cur][0][0];
#pragma unroll
        for (int ks = 0; ks < 2; ++ks) {
            unsigned int a0 = c0[2 * ks], b0 = c0[2 * ks + 1];
            unsigned int a1 = c1[2 * ks], b1 = c1[2 * ks + 1];
            plswap(a0, b0);            // a0 -> pb.d0 (lo-lane quad), b0 -> pb.d2 (hi-lane quad)
            plswap(a1, b1);
            u32x4 pw; pw[0] = a0; pw[1] = a1; pw[2] = b0; pw[3] = b1;
            const bf16x8 pb = __builtin_bit_cast(bf16x8, pw);
            const int phys = (ks * 2 + hi) ^ ((q32 >> 1) & 3);
            {
                const bf16x8 va = *(const bf16x8*)(vtile + q32 * 32 + phys * 8);
                o0 = __builtin_amdgcn_mfma_f32_32x32x16_bf16(va, pb, o0, 0, 0, 0);
            }
            {
                const bf16x8 va = *(const bf16x8*)(vtile + (32 + q32) * 32 + phys * 8);
                o1 = __builtin_amdgcn_mfma_f32_32x32x16_bf16(va, pb, o1, 0, 0, 0);
            }
        }
        cur ^= 1;
    }

    // o[dt][reg] = O^T[d = dt*32 + (reg&3) + 8*(reg>>2) + 4*hi][q]
    if (nsplit == 1) {
        const float inv = 1.f / lsum;
        float* op = Out + (size_t)q * ATT;
#pragma unroll
        for (int j = 0; j < 4; ++j) {
            f32x4 w0, w1;
#pragma unroll
            for (int r = 0; r < 4; ++r) { w0[r] = o0[4 * j + r] * inv; w1[r] = o1[4 * j + r] * inv; }
            *(f32x4*)(op + j * 8 + hi * 4)      = w0;
            *(f32x4*)(op + 32 + j * 8 + hi * 4) = w1;
        }
    } else {
        float* op = Opart + ((size_t)s * SEQ + q) * ATT;
#pragma unroll
        for (int j = 0; j < 4; ++j) {
            f32x4 w0, w1;
#pragma unroll
            for (int r = 0; r < 4; ++r) { w0[r] = o0[4 * j + r]; w1[r] = o1[4 * j + r]; }
            *(f32x4*)(op + j * 8 + hi * 4)      = w0;
            *(f32x4*)(op + 32 + j * 8 + hi * 4) = w1;
        }
        if (l < 32)
            Ml[(size_t)s * SEQ + q] = make_float2(m, lsum);
    }
}

// ---------------------------------------------------------------------------
// Kernel D: combine split-K partials (log2-domain m).
// ---------------------------------------------------------------------------
__global__ __launch_bounds__(256) void combine_kernel(
    const float* __restrict__ Opart,
    const float2* __restrict__ Ml,
    float* __restrict__ Out,
    int nsplit)
{
    const int t  = threadIdx.x;
    const int q  = blockIdx.x * 64 + (t >> 2);
    const int dg = t & 3;

    float M = -1e30f;
    for (int s = 0; s < nsplit; ++s)
        M = fmaxf(M, Ml[(size_t)s * SEQ + q].x);

    float den = 0.f;
    f32x4 acc[4] = {};
    for (int s = 0; s < nsplit; ++s) {
        const float2 ml = Ml[(size_t)s * SEQ + q];
        const float  w  = __builtin_amdgcn_exp2f(ml.x - M);
        den += w * ml.y;
        const float* op = Opart + ((size_t)s * SEQ + q) * ATT + dg * 16;
#pragma unroll
        for (int j = 0; j < 4; ++j) {
            const f32x4 v = *(const f32x4*)(op + j * 4);
            acc[j] += v * w;
        }
    }
    const float inv = 1.f / den;
#pragma unroll
    for (int j = 0; j < 4; ++j)
        *(f32x4*)(Out + (size_t)q * ATT + dg * 16 + j * 4) = acc[j] * inv;
}

// ---------------------------------------------------------------------------
extern "C" void kernel_launch(void* const* d_in, const int* in_sizes, int n_in,
                              void* d_out, int out_size, void* d_ws, size_t ws_size,
                              hipStream_t stream)
{
    const float* X  = (const float*)d_in[0];
    const float* Wq = (const float*)d_in[1];
    const float* bq = (const float*)d_in[2];
    const float* Wk = (const float*)d_in[3];
    const float* bk = (const float*)d_in[4];
    const float* Wv = (const float*)d_in[5];
    const float* bv = (const float*)d_in[6];
    float* Out = (float*)d_out;

    char* ws = (char*)d_ws;
    const size_t offQs = 0;
    const size_t offKb = offQs + (size_t)SEQ * ATT * 2;
    const size_t offVT = offKb + (size_t)SEQ * ATT * 2;
    const size_t offWb = offVT + (size_t)SEQ * ATT * 2;
    const size_t offbb = offWb + (size_t)192 * EMB * 2;
    const size_t base  = offbb + 1024;

    __bf16* Qs = (__bf16*)(ws + offQs);
    __bf16* Kb = (__bf16*)(ws + offKb);
    __bf16* VT = (__bf16*)(ws + offVT);
    __bf16* Wb = (__bf16*)(ws + offWb);
    float*  bb = (float*)(ws + offbb);

    const size_t per = (size_t)SEQ * ATT * 4 + (size_t)SEQ * 8;
    int nsplit = 1;
    const int cands[4] = {16, 8, 4, 2};
    for (int i = 0; i < 4; ++i)
        if (base + (size_t)cands[i] * per <= ws_size) { nsplit = cands[i]; break; }

    float*  Opart = (float*)(ws + base);
    float2* Ml    = (float2*)(ws + base + (size_t)nsplit * SEQ * ATT * 4);

    convertw_kernel<<<49, 256, 0, stream>>>(Wq, bq, Wk, bk, Wv, bv, Wb, bb);
    qkv_kernel<<<SEQ / 16, 256, 0, stream>>>(X, Wb, bb, Qs, Kb, VT);

    dim3 fgrid(SEQ / 128, nsplit);
    flash_kernel<<<fgrid, 256, 0, stream>>>(Qs, Kb, VT, Out, Opart, Ml, nsplit);

    if (nsplit > 1)
        combine_kernel<<<SEQ / 64, 256, 0, stream>>>(Opart, Ml, Out, nsplit);
}

// Round 5
// 67.132 us; speedup vs baseline: 3.5729x; 1.1254x over previous
//
#include <hip/hip_runtime.h>
#include <hip/hip_bf16.h>

#define SEQ 8192
#define EMB 512
#define ATT 64
#define SCALE 0.18033688f   // 0.125 * log2(e): scores land in log2 domain

typedef __bf16 bf16x8 __attribute__((ext_vector_type(8)));
typedef __bf16 bf16x4 __attribute__((ext_vector_type(4)));
typedef float  f32x4  __attribute__((ext_vector_type(4)));
typedef float  f32x16 __attribute__((ext_vector_type(16)));
typedef unsigned int u32x4 __attribute__((ext_vector_type(4)));
typedef unsigned int u32x2 __attribute__((ext_vector_type(2)));

static __device__ __forceinline__ unsigned int pkbf(float a, float b) {
    unsigned short ua = __builtin_bit_cast(unsigned short, (__bf16)a);
    unsigned short ub = __builtin_bit_cast(unsigned short, (__bf16)b);
    return ((unsigned int)ub << 16) | (unsigned int)ua;
}
static __device__ __forceinline__ bf16x8 cvt8(float4 a, float4 b) {
    bf16x8 r;
    r[0] = (__bf16)a.x; r[1] = (__bf16)a.y; r[2] = (__bf16)a.z; r[3] = (__bf16)a.w;
    r[4] = (__bf16)b.x; r[5] = (__bf16)b.y; r[6] = (__bf16)b.z; r[7] = (__bf16)b.w;
    return r;
}
static __device__ __forceinline__ void gll16(const void* g, void* l) {
    __builtin_amdgcn_global_load_lds(
        (const __attribute__((address_space(1))) unsigned int*)g,
        (__attribute__((address_space(3))) unsigned int*)l, 16, 0, 0);
}
static __device__ __forceinline__ void plswap(unsigned int& a, unsigned int& b) {
    asm("v_permlane32_swap_b32 %0, %1" : "+v"(a), "+v"(b));
}

// ---------------------------------------------------------------------------
// Kernel A: convert W/b -> Wb[192][512] bf16 (Wq rows prescaled by SCALE), bb.
// ---------------------------------------------------------------------------
__global__ __launch_bounds__(256) void convertw_kernel(
    const float* __restrict__ Wq, const float* __restrict__ bq,
    const float* __restrict__ Wk, const float* __restrict__ bk,
    const float* __restrict__ Wv, const float* __restrict__ bv,
    __bf16* __restrict__ Wb, float* __restrict__ bb)
{
    const int bid = blockIdx.x, tid = threadIdx.x;
    if (bid < 48) {
        const int e  = bid * 2048 + tid * 8;
        const int mm = e >> 15;
        const int wi = e & 32767;
        const float* Ws = mm == 0 ? Wq : (mm == 1 ? Wk : Wv);
        const float  s  = mm == 0 ? SCALE : 1.0f;
        float4 a0 = *(const float4*)(Ws + wi);
        float4 a1 = *(const float4*)(Ws + wi + 4);
        a0.x *= s; a0.y *= s; a0.z *= s; a0.w *= s;
        a1.x *= s; a1.y *= s; a1.z *= s; a1.w *= s;
        *(bf16x8*)(Wb + e) = cvt8(a0, a1);
    } else if (tid < 192) {
        const int mm = tid >> 6, c = tid & 63;
        const float* bs = mm == 0 ? bq : (mm == 1 ? bk : bv);
        bb[tid] = bs[c] * (mm == 0 ? SCALE : 1.0f);
    }
}

// ---------------------------------------------------------------------------
// Kernel B: QKV projection, LDS-tiled bf16 MFMA GEMM.
// grid = 256 blocks x 256 thr (4 waves). Block: 32 rows x 192 cols, K-step 32,
// double-buffered. W staged via global_load_lds (coalesced full-line sources,
// XOR slot swizzle: phys = s ^ (col&3), 2-way max conflict = free). X staged
// reg->LDS with fused fp32->bf16 convert (same swizzle on rows).
// Wave wv owns col-tiles wv*3..wv*3+2 and both 16-row tiles.
// ---------------------------------------------------------------------------
__global__ __launch_bounds__(256) void qkv_kernel(
    const float* __restrict__ X, const __bf16* __restrict__ Wb,
    const float* __restrict__ bb,
    __bf16* __restrict__ Qs, __bf16* __restrict__ Kb, __bf16* __restrict__ VT)
{
    __shared__ __bf16 Xt[2][32][32];    // 64B rows, phys 16B-slot = s ^ (row&3)
    __shared__ __bf16 Wt[2][192][32];   // 64B rows (row = W col), same swizzle

    const int tid = threadIdx.x;
    const int l = tid & 63, wv = tid >> 6;
    const int g = l >> 4, lr = l & 15;
    const int rowBase = blockIdx.x * 32;
    const int tt0 = wv * 3;

    // X staging: thread -> (row = tid>>3, halfslot hs = tid&7), f32x4 each
    const int xr = tid >> 3, xhs = tid & 7;
    const float* xsrc = X + (size_t)(rowBase + xr) * EMB + xhs * 4;
    const int xdst = xr * 64 + (((xhs >> 1) ^ (xr & 3)) << 4) + ((xhs & 1) << 3);

    // W staging: 3 gll16 issues per wave; issue i covers cols (i*4+wv)*16..+15
    int wOff[3];
#pragma unroll
    for (int i = 0; i < 3; ++i) {
        const int c = (i * 4 + wv) * 16 + (l >> 2);
        const int pp = l & 3;
        wOff[i] = c * EMB + ((pp ^ (c & 3)) << 3);
    }

    float bias[3];
#pragma unroll
    for (int j = 0; j < 3; ++j) bias[j] = bb[(tt0 + j) * 16 + lr];

    f32x4 acc[2][3] = {};

    // prologue: stage step 0 into buf 0
    {
        const f32x4 x0 = *(const f32x4*)(xsrc);
        u32x2 w; w[0] = pkbf(x0[0], x0[1]); w[1] = pkbf(x0[2], x0[3]);
        *(u32x2*)((char*)&Xt[0][0][0] + xdst) = w;
#pragma unroll
        for (int i = 0; i < 3; ++i)
            gll16(Wb + wOff[i], (char*)&Wt[0][0][0] + (i * 4 + wv) * 1024);
    }

    int cur = 0;
    for (int t = 0; t < 16; ++t) {
        __syncthreads();
        f32x4 xn = {};
        if (t < 15) {
#pragma unroll
            for (int i = 0; i < 3; ++i)
                gll16(Wb + wOff[i] + (t + 1) * 32, (char*)&Wt[cur ^ 1][0][0] + (i * 4 + wv) * 1024);
            xn = *(const f32x4*)(xsrc + (t + 1) * 32);
        }

        const int fo = (g ^ (lr & 3)) << 4;
        const bf16x8 af0 = *(const bf16x8*)((char*)&Xt[cur][0][0] + lr * 64 + fo);
        const bf16x8 af1 = *(const bf16x8*)((char*)&Xt[cur][0][0] + (16 + lr) * 64 + fo);
#pragma unroll
        for (int j = 0; j < 3; ++j) {
            const int col = (tt0 + j) * 16 + lr;
            const bf16x8 bfr = *(const bf16x8*)((char*)&Wt[cur][0][0] + col * 64 + fo);
            acc[0][j] = __builtin_amdgcn_mfma_f32_16x16x32_bf16(af0, bfr, acc[0][j], 0, 0, 0);
            acc[1][j] = __builtin_amdgcn_mfma_f32_16x16x32_bf16(af1, bfr, acc[1][j], 0, 0, 0);
        }

        if (t < 15) {
            u32x2 w; w[0] = pkbf(xn[0], xn[1]); w[1] = pkbf(xn[2], xn[3]);
            *(u32x2*)((char*)&Xt[cur ^ 1][0][0] + xdst) = w;
        }
        cur ^= 1;
    }

    // C layout: col = lr, row = base + g*4 + r
#pragma unroll
    for (int j = 0; j < 3; ++j) {
        const int tt = tt0 + j, mm = tt >> 2, col = (tt & 3) * 16 + lr;
#pragma unroll
        for (int rt = 0; rt < 2; ++rt) {
            const int row0 = rowBase + rt * 16 + g * 4;
            if (mm == 0) {
#pragma unroll
                for (int r = 0; r < 4; ++r)
                    Qs[(size_t)(row0 + r) * ATT + col] = (__bf16)(acc[rt][j][r] + bias[j]);
            } else if (mm == 1) {
#pragma unroll
                for (int r = 0; r < 4; ++r)
                    Kb[(size_t)(row0 + r) * ATT + col] = (__bf16)(acc[rt][j][r] + bias[j]);
            } else {
                bf16x4 v4;
#pragma unroll
                for (int r = 0; r < 4; ++r) v4[r] = (__bf16)(acc[rt][j][r] + bias[j]);
                *(bf16x4*)(VT + (size_t)col * SEQ + row0) = v4;
            }
        }
    }
}

// ---------------------------------------------------------------------------
// Kernel C: flash attention, 32x32x16 MFMA, QBLK=32/wave, 4 waves, KVBLK=64
// (processed as two 32-key halves sharing one staged tile -> half the
// barriers/stage-issues per key vs round 4). K/V double-buffered in LDS via
// global_load_lds; both tiles [64][64] with phys slot = s ^ (row&7)
// (conflict-free octets, source-preswizzled). P routed to PV B-frags via
// pack + v_permlane32_swap (no LDS). Split-K partials in bf16.
// ---------------------------------------------------------------------------
__global__ __launch_bounds__(256, 4) void flash_kernel(
    const __bf16* __restrict__ Qs,
    const __bf16* __restrict__ Kb,
    const __bf16* __restrict__ VT,
    float* __restrict__ Out,
    __bf16* __restrict__ Opart,
    float2* __restrict__ Ml,
    int nsplit)
{
    __shared__ __bf16 Kt[2][64][64];   // row = key
    __shared__ __bf16 Vt[2][64][64];   // row = d

    const int l   = threadIdx.x & 63;
    const int wv  = threadIdx.x >> 6;
    const int q32 = l & 31;
    const int hi  = l >> 5;
    const int q   = blockIdx.x * 128 + wv * 32 + q32;
    const int s   = blockIdx.y;
    const int KS  = SEQ / nsplit;
    const int k0  = s * KS;
    const int nt  = KS / 64;
    const int swz = q32 & 7;

    // stage geometry: wave covers rows {wv*8..+7} and {32+wv*8..+7} of each tile
    const int rA = wv * 8 + (l >> 3);
    const int rB = 32 + rA;
    const int p  = l & 7;
    const int kOffA = rA * ATT + ((p ^ (rA & 7)) << 3);
    const int kOffB = rB * ATT + ((p ^ (rB & 7)) << 3);
    const int vOffA = rA * SEQ + ((p ^ (rA & 7)) << 3);
    const int vOffB = rB * SEQ + ((p ^ (rB & 7)) << 3);

    bf16x8 qf[4];
#pragma unroll
    for (int dk = 0; dk < 4; ++dk)
        qf[dk] = *(const bf16x8*)(Qs + (size_t)q * ATT + dk * 16 + hi * 8);

    float m = -1e30f, lsum = 0.f;
    f32x16 o0 = {}, o1 = {};

    gll16(Kb + (size_t)k0 * ATT + kOffA, &Kt[0][wv * 8][0]);
    gll16(Kb + (size_t)k0 * ATT + kOffB, &Kt[0][32 + wv * 8][0]);
    gll16(VT + (size_t)vOffA + k0,       &Vt[0][wv * 8][0]);
    gll16(VT + (size_t)vOffB + k0,       &Vt[0][32 + wv * 8][0]);

    int cur = 0;
    for (int t = 0; t < nt; ++t) {
        __syncthreads();               // buf[cur] staged (vmcnt drained); prev reads done
        if (t + 1 < nt) {
            const size_t kb = (size_t)k0 + (size_t)(t + 1) * 64;
            gll16(Kb + kb * ATT + kOffA, &Kt[cur ^ 1][wv * 8][0]);
            gll16(Kb + kb * ATT + kOffB, &Kt[cur ^ 1][32 + wv * 8][0]);
            gll16(VT + (size_t)vOffA + kb, &Vt[cur ^ 1][wv * 8][0]);
            gll16(VT + (size_t)vOffB + kb, &Vt[cur ^ 1][32 + wv * 8][0]);
        }
        const __bf16* ktile = &Kt[cur][0][0];
        const __bf16* vtile = &Vt[cur][0][0];

#pragma unroll
        for (int h = 0; h < 2; ++h) {
            // ---- QK^T: S^T[key][q] over 4 d-chunks ----
            f32x16 st = {};
#pragma unroll
            for (int dk = 0; dk < 4; ++dk) {
                const int phys = (dk * 2 + hi) ^ swz;
                const bf16x8 ka = *(const bf16x8*)(ktile + (h * 32 + q32) * 64 + phys * 8);
                st = __builtin_amdgcn_mfma_f32_32x32x16_bf16(ka, qf[dk], st, 0, 0, 0);
            }
            // st[reg] = S^T[key = h*32 + (reg&3) + 8*(reg>>2) + 4*hi][q]

            // ---- online softmax (defer-max, THR ~ 8*log2e) ----
            float m0 = fmaxf(fmaxf(st[0], st[1]), fmaxf(st[2], st[3]));
            float m1 = fmaxf(fmaxf(st[4], st[5]), fmaxf(st[6], st[7]));
            float m2 = fmaxf(fmaxf(st[8], st[9]), fmaxf(st[10], st[11]));
            float m3 = fmaxf(fmaxf(st[12], st[13]), fmaxf(st[14], st[15]));
            float cm = fmaxf(fmaxf(m0, m1), fmaxf(m2, m3));
            cm = fmaxf(cm, __shfl_xor(cm, 32));
            if (__any(cm > m + 11.5f)) {
                const float nm = fmaxf(m, cm);
                const float al = __builtin_amdgcn_exp2f(m - nm);
                lsum *= al;
#pragma unroll
                for (int r = 0; r < 16; ++r) { o0[r] *= al; o1[r] *= al; }
                m = nm;
            }

#pragma unroll
            for (int r = 0; r < 16; ++r) st[r] = __builtin_amdgcn_exp2f(st[r] - m);
            float ps = (((st[0] + st[1]) + (st[2] + st[3])) + ((st[4] + st[5]) + (st[6] + st[7]))) +
                       (((st[8] + st[9]) + (st[10] + st[11])) + ((st[12] + st[13]) + (st[14] + st[15])));
            ps += __shfl_xor(ps, 32);
            lsum += ps;

            unsigned int c0[4], c1[4];
#pragma unroll
            for (int i = 0; i < 4; ++i) {
                c0[i] = pkbf(st[4 * i],     st[4 * i + 1]);
                c1[i] = pkbf(st[4 * i + 2], st[4 * i + 3]);
            }

            // ---- PV: O^T += V^T x P^T ----
#pragma unroll
            for (int ks = 0; ks < 2; ++ks) {
                unsigned int a0 = c0[2 * ks], b0 = c0[2 * ks + 1];
                unsigned int a1 = c1[2 * ks], b1 = c1[2 * ks + 1];
                plswap(a0, b0);
                plswap(a1, b1);
                u32x4 pw; pw[0] = a0; pw[1] = a1; pw[2] = b0; pw[3] = b1;
                const bf16x8 pb = __builtin_bit_cast(bf16x8, pw);
                const int physv = (h * 4 + ks * 2 + hi) ^ swz;
                {
                    const bf16x8 va = *(const bf16x8*)(vtile + q32 * 64 + physv * 8);
                    o0 = __builtin_amdgcn_mfma_f32_32x32x16_bf16(va, pb, o0, 0, 0, 0);
                }
                {
                    const bf16x8 va = *(const bf16x8*)(vtile + (32 + q32) * 64 + physv * 8);
                    o1 = __builtin_amdgcn_mfma_f32_32x32x16_bf16(va, pb, o1, 0, 0, 0);
                }
            }
        }
        cur ^= 1;
    }

    // o[reg] -> d = dt*32 + (reg&3) + 8*(reg>>2) + 4*hi, col q
    if (nsplit == 1) {
        const float inv = 1.f / lsum;
        float* op = Out + (size_t)q * ATT;
#pragma unroll
        for (int j = 0; j < 4; ++j) {
            f32x4 w0, w1;
#pragma unroll
            for (int r = 0; r < 4; ++r) { w0[r] = o0[4 * j + r] * inv; w1[r] = o1[4 * j + r] * inv; }
            *(f32x4*)(op + j * 8 + hi * 4)      = w0;
            *(f32x4*)(op + 32 + j * 8 + hi * 4) = w1;
        }
    } else {
        __bf16* op = Opart + ((size_t)s * SEQ + q) * ATT;
#pragma unroll
        for (int j = 0; j < 4; ++j) {
            bf16x4 w0, w1;
#pragma unroll
            for (int r = 0; r < 4; ++r) { w0[r] = (__bf16)o0[4 * j + r]; w1[r] = (__bf16)o1[4 * j + r]; }
            *(bf16x4*)(op + j * 8 + hi * 4)      = w0;
            *(bf16x4*)(op + 32 + j * 8 + hi * 4) = w1;
        }
        if (l < 32)
            Ml[(size_t)s * SEQ + q] = make_float2(m, lsum);
    }
}

// ---------------------------------------------------------------------------
// Kernel D: combine split-K partials (bf16 partials, log2-domain m).
// ---------------------------------------------------------------------------
__global__ __launch_bounds__(256) void combine_kernel(
    const __bf16* __restrict__ Opart,
    const float2* __restrict__ Ml,
    float* __restrict__ Out,
    int nsplit)
{
    const int t  = threadIdx.x;
    const int q  = blockIdx.x * 64 + (t >> 2);
    const int dg = t & 3;

    float M = -1e30f;
    for (int s = 0; s < nsplit; ++s)
        M = fmaxf(M, Ml[(size_t)s * SEQ + q].x);

    float den = 0.f;
    f32x4 acc[4] = {};
    for (int s = 0; s < nsplit; ++s) {
        const float2 ml = Ml[(size_t)s * SEQ + q];
        const float  w  = __builtin_amdgcn_exp2f(ml.x - M);
        den += w * ml.y;
        const __bf16* op = Opart + ((size_t)s * SEQ + q) * ATT + dg * 16;
        const bf16x8 v0 = *(const bf16x8*)(op);
        const bf16x8 v1 = *(const bf16x8*)(op + 8);
#pragma unroll
        for (int j = 0; j < 2; ++j)
#pragma unroll
            for (int r = 0; r < 4; ++r) {
                acc[j][r]     += w * (float)v0[j * 4 + r];
                acc[2 + j][r] += w * (float)v1[j * 4 + r];
            }
    }
    const float inv = 1.f / den;
#pragma unroll
    for (int j = 0; j < 4; ++j)
        *(f32x4*)(Out + (size_t)q * ATT + dg * 16 + j * 4) = acc[j] * inv;
}

// ---------------------------------------------------------------------------
extern "C" void kernel_launch(void* const* d_in, const int* in_sizes, int n_in,
                              void* d_out, int out_size, void* d_ws, size_t ws_size,
                              hipStream_t stream)
{
    const float* X  = (const float*)d_in[0];
    const float* Wq = (const float*)d_in[1];
    const float* bq = (const float*)d_in[2];
    const float* Wk = (const float*)d_in[3];
    const float* bk = (const float*)d_in[4];
    const float* Wv = (const float*)d_in[5];
    const float* bv = (const float*)d_in[6];
    float* Out = (float*)d_out;

    char* ws = (char*)d_ws;
    const size_t offQs = 0;
    const size_t offKb = offQs + (size_t)SEQ * ATT * 2;
    const size_t offVT = offKb + (size_t)SEQ * ATT * 2;
    const size_t offWb = offVT + (size_t)SEQ * ATT * 2;
    const size_t offbb = offWb + (size_t)192 * EMB * 2;
    const size_t base  = offbb + 1024;

    __bf16* Qs = (__bf16*)(ws + offQs);
    __bf16* Kb = (__bf16*)(ws + offKb);
    __bf16* VT = (__bf16*)(ws + offVT);
    __bf16* Wb = (__bf16*)(ws + offWb);
    float*  bb = (float*)(ws + offbb);

    const size_t per = (size_t)SEQ * ATT * 2 + (size_t)SEQ * 8;   // bf16 Opart + Ml
    int nsplit = 1;
    const int cands[4] = {16, 8, 4, 2};
    for (int i = 0; i < 4; ++i)
        if (base + (size_t)cands[i] * per <= ws_size) { nsplit = cands[i]; break; }

    __bf16* Opart = (__bf16*)(ws + base);
    float2* Ml    = (float2*)(ws + base + (size_t)nsplit * SEQ * ATT * 2);

    convertw_kernel<<<49, 256, 0, stream>>>(Wq, bq, Wk, bk, Wv, bv, Wb, bb);
    qkv_kernel<<<256, 256, 0, stream>>>(X, Wb, bb, Qs, Kb, VT);

    dim3 fgrid(SEQ / 128, nsplit);
    flash_kernel<<<fgrid, 256, 0, stream>>>(Qs, Kb, VT, Out, Opart, Ml, nsplit);

    if (nsplit > 1)
        combine_kernel<<<SEQ / 64, 256, 0, stream>>>(Opart, Ml, Out, nsplit);
}